// Round 10
// baseline (1019.105 us; speedup 1.0000x reference)
//
#include <hip/hip_runtime.h>
#include <stdint.h>

#define DEVI __device__ __forceinline__

typedef __attribute__((ext_vector_type(8))) short bf16x8;   // 8 bf16 (4 VGPRs)
typedef __attribute__((ext_vector_type(4))) float f32x4;    // MFMA C/D

static constexpr int D = 4096;    // d_in == d_out == K == N
static constexpr int M = 16384;   // bs*seq rows

// exact RNE float -> bf16 bits
DEVI unsigned short f2bf(float f) {
  union { float f; unsigned u; } a; a.f = f;
  unsigned r = a.u + 0x7fffu + ((a.u >> 16) & 1u);
  return (unsigned short)(r >> 16);
}

// async global->LDS, 16B per lane; LDS dest is wave-uniform base + lane*16
DEVI void gload_lds16(const void* g, void* l) {
  __builtin_amdgcn_global_load_lds(
      (__attribute__((address_space(1))) void*)(uintptr_t)g,
      (__attribute__((address_space(3))) void*)l,
      16, 0, 0);
}

DEVI f32x4 MFMA(bf16x8 a, bf16x8 b, f32x4 c) {
  return __builtin_amdgcn_mfma_f32_16x16x32_bf16(a, b, c, 0, 0, 0);
}

#define ASM_BAR()    asm volatile("s_barrier" ::: "memory")
#define WAIT_VM(N)   asm volatile("s_waitcnt vmcnt(" #N ")" ::: "memory")
#define SGB          __builtin_amdgcn_sched_group_barrier

// ---------------- Kernel A: w_norm (double) + W -> bf16 ----------------
__global__ __launch_bounds__(256) void k_wnorm(const float* __restrict__ w,
                                               double* __restrict__ wn_d,
                                               unsigned short* __restrict__ wbf) {
  const int col = blockIdx.x * 256 + threadIdx.x;
  const int r0 = blockIdx.y * 256;
  double s = 0.0;
  for (int r = r0; r < r0 + 256; ++r) {
    float v = w[(size_t)r * D + col];
    wbf[(size_t)r * D + col] = f2bf(v);
    s += (double)v * (double)v;
  }
  atomicAdd(&wn_d[col], s);
}

__global__ void k_wnf(const double* __restrict__ wn_d, float* __restrict__ wn_f) {
  int i = blockIdx.x * blockDim.x + threadIdx.x;
  if (i < D) wn_f[i] = (float)wn_d[i];
}

// ---------------- Kernel B: 2:4 prune + variance-correct, -> bf16 -------
__global__ __launch_bounds__(256) void k_prune(const float* __restrict__ x,
                                               const float* __restrict__ wn_f,
                                               unsigned short* __restrict__ xs) {
  const int row = blockIdx.x;
  const float* xr = x + (size_t)row * D;
  unsigned short* xo = xs + (size_t)row * D;
  const int t = threadIdx.x;

  float kept[4][4];
  float sx = 0.f, sxx = 0.f, ss = 0.f, sss = 0.f;

#pragma unroll
  for (int i = 0; i < 4; ++i) {
    const int g = t + i * 256;
    const float4 v  = *(const float4*)(xr + 4 * (size_t)g);
    const float4 wv = *(const float4*)(wn_f + 4 * (size_t)g);
    float xv[4] = {v.x, v.y, v.z, v.w};
    float m[4]  = {fabsf(v.x) * wv.x, fabsf(v.y) * wv.y,
                   fabsf(v.z) * wv.z, fabsf(v.w) * wv.w};
    int i1 = 0;
#pragma unroll
    for (int j = 1; j < 4; ++j) if (m[j] > m[i1]) i1 = j;
    int i2 = (i1 == 0) ? 1 : 0;
#pragma unroll
    for (int j = 0; j < 4; ++j) if (j != i1 && j != i2 && m[j] > m[i2]) i2 = j;
#pragma unroll
    for (int j = 0; j < 4; ++j) {
      bool keep = (j == i1) || (j == i2);
      float kv = keep ? xv[j] : 0.f;
      kept[i][j] = kv;
      sx += xv[j]; sxx += xv[j] * xv[j]; ss += kv; sss += kv * kv;
    }
  }

#pragma unroll
  for (int o = 32; o > 0; o >>= 1) {
    sx  += __shfl_down(sx, o);
    sxx += __shfl_down(sxx, o);
    ss  += __shfl_down(ss, o);
    sss += __shfl_down(sss, o);
  }
  __shared__ float wp[4][4];
  __shared__ float s_scale;
  const int wid = t >> 6, lane = t & 63;
  if (lane == 0) { wp[wid][0] = sx; wp[wid][1] = sxx; wp[wid][2] = ss; wp[wid][3] = sss; }
  __syncthreads();
  if (t == 0) {
    float SX = 0, SXX = 0, SS = 0, SSS = 0;
    for (int u = 0; u < 4; ++u) { SX += wp[u][0]; SXX += wp[u][1]; SS += wp[u][2]; SSS += wp[u][3]; }
    float vx = SXX - SX * SX * (1.f / 4096.f);
    float vs = SSS - SS * SS * (1.f / 4096.f);
    s_scale = sqrtf(vx / vs);
  }
  __syncthreads();
  const float sc = s_scale;

#pragma unroll
  for (int i = 0; i < 4; ++i) {
    const int g = t + i * 256;
    ushort4 o;
    o.x = f2bf(kept[i][0] * sc);
    o.y = f2bf(kept[i][1] * sc);
    o.z = f2bf(kept[i][2] * sc);
    o.w = f2bf(kept[i][3] * sc);
    *(ushort4*)(xo + 4 * (size_t)g) = o;
  }
}

// ---------------- Kernel C: bf16 GEMM, 256x256 tile, B direct-from-L2 ----
// C[m][n] = sum_k A[m][k]*B[n][k].  BK=32. A: 3-deep circular LDS regions
// (256x32 bf16 = 16KB, chunk-swizzled; 4x inter-wave reuse). B: NO LDS —
// each wave loads its 4 B-fragments (16B/lane, layout row=lane&15,
// k=(lane>>4)*8 == exactly the MFMA B-operand) straight from global (L2-
// resident), double-buffered one step ahead on the VMEM pipe, which is
// proven to overlap MFMA (staging always has). DS pipe drops 96->64 reads
// + half the gload-writes per step. Top-of-step vmcnt(2) FIFO retires
// stageA(t)+B(t) exactly (issue order per step: B(t+1) x4, stageA(t+2) x2).
__global__ __launch_bounds__(512) void k_gemm(const unsigned short* __restrict__ A,  // [M,K]
                                              const unsigned short* __restrict__ B,  // [N,K]
                                              float* __restrict__ C) {               // [M,N]
  extern __shared__ char smem[];   // 49152 bytes (3 A regions)

  const int tid  = threadIdx.x;
  const int lane = tid & 63;
  const int wid  = tid >> 6;
  const int wr   = wid >> 2;   // 0..1  (row half)
  const int wc   = wid & 3;    // 0..3  (col quarter)

  // T1: XCD swizzle (1024 blocks, divisible by 8)
  const int bid = blockIdx.x;
  const int swz = (bid & 7) * 128 + (bid >> 3);
  const int m0 = (swz >> 4) * 256;   // 64 row tiles
  const int n0 = (swz & 15) * 256;   // 16 col tiles

  // A staging: region 256 rows x 32 k; thread t -> row t>>2, 16B chunk t&3,
  // chunk XOR-swizzled via pre-swizzled GLOBAL source (LDS dest linear).
  const int rs = tid >> 2;                                  // 0..127
  const int ks = ((tid & 3) ^ ((tid >> 3) & 3)) * 8;        // swizzled k-elem off
  const unsigned short* Ar0 = A + (size_t)(m0 + rs) * D + ks;
  const unsigned short* Ar1 = Ar0 + (size_t)128 * D;
  char* ldst = smem + tid * 16;

  // A frag-read byte offset within a region (row*64B + swizzled 16B chunk)
  const int swz16 = (((lane >> 4) ^ ((lane >> 1) & 3)) << 4);
  const int aRd = (wr * 128 + (lane & 15)) * 64 + swz16;    // + fm*1024 + region

  // B direct-load base: row (n-index) = n0 + wc*64 + fn*16 + (lane&15),
  // k-chunk = (lane>>4)*8 elems; one 16B load == one MFMA B-fragment.
  const unsigned short* Bf = B + (size_t)(n0 + wc * 64 + (lane & 15)) * D
                               + ((lane >> 4) << 3);

#define STAGE_A(p, kt) do {                                          \
    const int _ko = (kt) * 32;                                       \
    gload_lds16(Ar0 + _ko, ldst + (p) * 16384);                      \
    gload_lds16(Ar1 + _ko, ldst + (p) * 16384 + 8192);               \
  } while (0)

#define LOADB(NB, kt) do {                                           \
    _Pragma("unroll")                                                \
    for (int fn = 0; fn < 4; ++fn)                                   \
      NB[fn] = *(const bf16x8*)(Bf + (size_t)fn * 16 * D + (kt) * 32); \
  } while (0)

#define MFMA32(xb) do {                                              \
    __builtin_amdgcn_s_setprio(1);                                   \
    _Pragma("unroll")                                                \
    for (int fm = 0; fm < 8; ++fm)                                   \
      _Pragma("unroll")                                              \
      for (int fn = 0; fn < 4; ++fn)                                 \
        acc[fm][fn] = MFMA(ca[fm], xb[fn], acc[fm][fn]);             \
    __builtin_amdgcn_s_setprio(0);                                   \
  } while (0)

// one K-step: vmcnt(2) retires stageA(t)+B(t); barrier; 8 A ds_reads
// (in-phase, compiler inserts counted lgkm before MFMAs); B(t+1) loads;
// stage A k(t+2); 32 MFMA. SGB interleaves DS/VMEM under the MFMA cluster.
#define SUBSTEP(CB, NB) do {                                         \
    WAIT_VM(2);                                                      \
    ASM_BAR();                                                       \
    _Pragma("unroll")                                                \
    for (int fm = 0; fm < 8; ++fm)                                   \
      ca[fm] = *(const bf16x8*)(smem + rp * 16384 + aRd + fm * 1024); \
    LOADB(NB, kbn);                                                  \
    STAGE_A(sp, kst);                                                \
    MFMA32(CB);                                                      \
    _Pragma("unroll")                                                \
    for (int i = 0; i < 8; ++i) { SGB(0x100, 1, 0); SGB(0x8, 2, 0); } \
    _Pragma("unroll")                                                \
    for (int i = 0; i < 6; ++i) { SGB(0x10, 1, 0); SGB(0x8, 2, 0); } \
    SGB(0x8, 4, 0);                                                  \
    rp = (rp == 2) ? 0 : rp + 1;                                     \
    sp = (sp == 2) ? 0 : sp + 1;                                     \
    kst = (kst < 127) ? kst + 1 : 127;                               \
    kbn = (kbn < 127) ? kbn + 1 : 127;                               \
  } while (0)

  f32x4 acc[8][4] = {};
  bf16x8 ca[8], cb[4], nb[4];

  // ---- prologue: FIFO order stageA(k0), B(k0), stageA(k1) ----
  STAGE_A(0, 0);
  LOADB(cb, 0);
  STAGE_A(1, 1);

  int rp = 0, sp = 2, kst = 2, kbn = 1;
  for (int d = 0; d < 64; ++d) {
    SUBSTEP(cb, nb);
    SUBSTEP(nb, cb);
  }
#undef SUBSTEP
#undef MFMA32
#undef LOADB
#undef STAGE_A

  // ---- epilogue: C/D layout col=lane&15, row=(lane>>4)*4+i ----
  const int orow = (lane >> 4) * 4;
  const int ocol = lane & 15;
  float* Cw = C + (size_t)(m0 + wr * 128 + orow) * D + n0 + wc * 64 + ocol;
#pragma unroll
  for (int fm = 0; fm < 8; ++fm)
#pragma unroll
    for (int fn = 0; fn < 4; ++fn)
#pragma unroll
      for (int i = 0; i < 4; ++i)
        Cw[(size_t)(fm * 16 + i) * D + fn * 16] = acc[fm][fn][i];
}

extern "C" void kernel_launch(void* const* d_in, const int* in_sizes, int n_in,
                              void* d_out, int out_size, void* d_ws, size_t ws_size,
                              hipStream_t stream) {
  const float* x = (const float*)d_in[0];   // [4,4096,4096] fp32
  const float* w = (const float*)d_in[1];   // [4096,4096] fp32
  float* out = (float*)d_out;               // [16384,4096] fp32

  char* ws = (char*)d_ws;
  double* wn_d = (double*)ws;                                   // 32 KB
  float* wn_f = (float*)(ws + 32768);                           // 16 KB
  unsigned short* wbf = (unsigned short*)(ws + 49152);          // 33.5 MB
  unsigned short* xsb = (unsigned short*)(ws + 49152 + (size_t)D * D * 2);  // 134 MB

  hipMemsetAsync(wn_d, 0, D * sizeof(double), stream);
  k_wnorm<<<dim3(16, 16), 256, 0, stream>>>(w, wn_d, wbf);
  k_wnf<<<16, 256, 0, stream>>>(wn_d, wn_f);
  k_prune<<<M, 256, 0, stream>>>(x, wn_f, xsb);
  k_gemm<<<dim3((M / 256) * (D / 256)), 512, 49152, stream>>>(xsb, wbf, out);
}